// Round 5
// baseline (594.779 us; speedup 1.0000x reference)
//
#include <hip/hip_runtime.h>
#include <hip/hip_bf16.h>
#include <math.h>

#define BATCH 64
#define TLEN 512
#define DIM 768
#define NLAB 50

typedef __attribute__((ext_vector_type(8))) short short8;   // 8 bf16 (4 VGPRs)
typedef __attribute__((ext_vector_type(4))) float f32x4;    // MFMA acc

__device__ __forceinline__ unsigned short f2bf(float f) {
    unsigned int u = __float_as_uint(f);
    return (unsigned short)((u + 0x7FFFu + ((u >> 16) & 1u)) >> 16);
}

// single-wave LDS fence: legal ONLY for 64-thread (one-wave) blocks.
__device__ __forceinline__ void wave_lds_fence() {
    __asm__ __volatile__("s_waitcnt lgkmcnt(0)" ::: "memory");
    __builtin_amdgcn_wave_barrier();
}

// ---------------------------------------------------------------------------
// prep: W fp32 [768 x 50] -> Bt bf16 [64 cols][768 k]; zero out[0] for atomics
// ---------------------------------------------------------------------------
__global__ __launch_bounds__(256) void wprep_kernel(const float* __restrict__ W,
                                                    unsigned short* __restrict__ Bt,
                                                    float* __restrict__ out0) {
    int idx = blockIdx.x * 256 + threadIdx.x;
    if (idx == 0) out0[0] = 0.f;
    if (idx < 64 * DIM) {
        int c = idx / DIM;
        int k = idx - c * DIM;
        float v = (c < NLAB) ? W[k * NLAB + c] : 0.f;
        Bt[idx] = f2bf(v);
    }
}

// ---------------------------------------------------------------------------
// GEMM (unchanged): 512 thr / 8 waves, tile 128x64, dbuf LDS.
// ---------------------------------------------------------------------------
#define AST 36
#define BSTC 40

__global__ __launch_bounds__(512)
void gemm_kernel(
    const float* __restrict__ A,
    const unsigned short* __restrict__ Bt,
    const float* __restrict__ bias,
    float* __restrict__ out)
{
    __shared__ float As[2][128 * AST];
    __shared__ short Bs[2][64 * BSTC];

    const int tid = threadIdx.x;
    const int wave = tid >> 6;
    const int lane = tid & 63;
    const int m = lane & 15;
    const int q = lane >> 4;
    const int row0 = blockIdx.x * 128;

    const int r0s = tid >> 2;
    const int c0s = (tid & 3) * 8;
    const int bcol = tid >> 3;
    const int bkk = (tid & 7) * 4;

    f32x4 acc0 = {0.f,0.f,0.f,0.f}, acc1 = {0.f,0.f,0.f,0.f};
    f32x4 acc2 = {0.f,0.f,0.f,0.f}, acc3 = {0.f,0.f,0.f,0.f};

    {
        *(float4*)&As[0][r0s * AST + c0s]     = *(const float4*)(A + (size_t)(row0 + r0s) * DIM + c0s);
        *(float4*)&As[0][r0s * AST + c0s + 4] = *(const float4*)(A + (size_t)(row0 + r0s) * DIM + c0s + 4);
        *(short4*)&Bs[0][bcol * BSTC + bkk]   = *(const short4*)(Bt + (size_t)bcol * DIM + bkk);
    }
    __syncthreads();

    int buf = 0;
    for (int ch = 0; ch < DIM / 32; ++ch) {
        const int k0n = (ch + 1) * 32;
        const bool havenext = (ch < DIM / 32 - 1);
        float4 pa0, pa1;
        short4 pb;
        if (havenext) {
            pa0 = *(const float4*)(A + (size_t)(row0 + r0s) * DIM + k0n + c0s);
            pa1 = *(const float4*)(A + (size_t)(row0 + r0s) * DIM + k0n + c0s + 4);
            pb  = *(const short4*)(Bt + (size_t)bcol * DIM + k0n + bkk);
        }

        const short8 bq0 = *(const short8*)&Bs[buf][( 0 + m) * BSTC + q * 8];
        const short8 bq1 = *(const short8*)&Bs[buf][(16 + m) * BSTC + q * 8];
        const short8 bq2 = *(const short8*)&Bs[buf][(32 + m) * BSTC + q * 8];
        const short8 bq3 = *(const short8*)&Bs[buf][(48 + m) * BSTC + q * 8];

        {
            const int rr = wave * 16 + m;
            const float4 xa = *(const float4*)&As[buf][rr * AST + q * 8];
            const float4 xb = *(const float4*)&As[buf][rr * AST + q * 8 + 4];
            short8 af;
            af[0] = (short)f2bf(xa.x); af[1] = (short)f2bf(xa.y);
            af[2] = (short)f2bf(xa.z); af[3] = (short)f2bf(xa.w);
            af[4] = (short)f2bf(xb.x); af[5] = (short)f2bf(xb.y);
            af[6] = (short)f2bf(xb.z); af[7] = (short)f2bf(xb.w);
            acc0 = __builtin_amdgcn_mfma_f32_16x16x32_bf16(af, bq0, acc0, 0, 0, 0);
            acc1 = __builtin_amdgcn_mfma_f32_16x16x32_bf16(af, bq1, acc1, 0, 0, 0);
            acc2 = __builtin_amdgcn_mfma_f32_16x16x32_bf16(af, bq2, acc2, 0, 0, 0);
            acc3 = __builtin_amdgcn_mfma_f32_16x16x32_bf16(af, bq3, acc3, 0, 0, 0);
        }

        if (havenext) {
            const int nb = buf ^ 1;
            *(float4*)&As[nb][r0s * AST + c0s]     = pa0;
            *(float4*)&As[nb][r0s * AST + c0s + 4] = pa1;
            *(short4*)&Bs[nb][bcol * BSTC + bkk]   = pb;
        }
        __syncthreads();
        buf ^= 1;
    }

    const int rb = row0 + wave * 16 + q * 4;
#pragma unroll
    for (int nt = 0; nt < 4; ++nt) {
        const f32x4 av = (nt == 0) ? acc0 : (nt == 1) ? acc1 : (nt == 2) ? acc2 : acc3;
        const int col = nt * 16 + m;
        if (col < NLAB) {
            const float bv = bias[col];
#pragma unroll
            for (int r = 0; r < 4; ++r)
                out[(size_t)(rb + r) * NLAB + col] = av[r] + bv;
        }
    }
}

// ---------------------------------------------------------------------------
// CRF v11b: batched-MFMA scan (v11 with __exp2f -> __builtin_amdgcn_exp2f).
// 4 blocks x 1 wave; 16 batches/wave. State X [50 labels x 16 batch] bf16 in
// LDS (XOR-swizzled), consumed as the MFMA B-operand. Per step: r = E^T X via
// 16 mfma_16x16x32_bf16 (E split hi+lo bf16 => fp32-grade transition matrix),
// emission+rescale fused as exp2(em*log2e - log2(v)) in C-layout fp32,
// cvt_pk -> 8 ds_write_b32, fence, 2 ds_read_b128 back into B-frags.
// Scale v = X[b][0] via off-chain ds_read_u16; A += log2(v)*ln2.
// Per-batch mask: predicate writes + A-accum (frozen batches keep X).
// ---------------------------------------------------------------------------
#define LOG2E 1.44269504088896340736f
#define LN2   0.69314718055994530942f

__global__ __launch_bounds__(64) __attribute__((amdgpu_waves_per_eu(1, 1)))
void crf_kernel(
    const float* __restrict__ logits,
    const int* __restrict__ labels,
    const void* __restrict__ maskp,
    const float* __restrict__ startT,
    const float* __restrict__ endT,
    const float* __restrict__ trans,
    float* __restrict__ out0) {
    const int lane = threadIdx.x;
    const int b16 = lane & 15;           // batch within block
    const int g = lane >> 4;             // quad group
    const int b = blockIdx.x * 16 + b16; // global batch

    __shared__ __align__(16) unsigned short X[16 * 64]; // [batch][label] bf16
    char* xc = (char*)X;

    // ---- len_b: chunked mask scan (chunk c = g covers 128 t's) ----
    const int probe = ((const int*)maskp)[0];
    int len = 0;
    {
        const int t0 = g * 128;
        if (probe == 1) {
            const int* mk = (const int*)maskp + (size_t)b * TLEN + t0;
#pragma unroll 8
            for (int i = 0; i < 128; ++i) len += (mk[i] != 0);
        } else if (probe == 0x01010101) {
            const unsigned char* mk = (const unsigned char*)maskp + (size_t)b * TLEN + t0;
#pragma unroll 8
            for (int i = 0; i < 128; ++i) len += (mk[i] != 0);
        } else if (probe == 0x3F803F80) {
            const unsigned short* mk = (const unsigned short*)maskp + (size_t)b * TLEN + t0;
#pragma unroll 8
            for (int i = 0; i < 128; ++i) len += (mk[i] != 0);
        } else {
            const float* mk = (const float*)maskp + (size_t)b * TLEN + t0;
#pragma unroll 8
            for (int i = 0; i < 128; ++i) len += (mk[i] != 0.f);
        }
    }
    len += __shfl_xor(len, 16, 64);
    len += __shfl_xor(len, 32, 64);
    int lenmax = len;
    { int o = __shfl_xor(lenmax, 1, 64); lenmax = lenmax > o ? lenmax : o; }
    { int o = __shfl_xor(lenmax, 2, 64); lenmax = lenmax > o ? lenmax : o; }
    { int o = __shfl_xor(lenmax, 4, 64); lenmax = lenmax > o ? lenmax : o; }
    { int o = __shfl_xor(lenmax, 8, 64); lenmax = lenmax > o ? lenmax : o; }

    // ---- E^T fragments: A[m][k] = exp(trans[k][m]), hi/lo bf16, zero-pad ----
    short8 ah00, ah01, ah02, ah03, ah10, ah11, ah12, ah13;
    short8 al00, al01, al02, al03, al10, al11, al12, al13;
#define MKFRAG(DH, DL, KT, MT) { short8 h, l;                                   \
    _Pragma("unroll")                                                           \
    for (int j = 0; j < 8; ++j) {                                               \
        const int k = 32 * KT + 8 * g + j; const int m = 16 * MT + b16;         \
        float e = 0.f;                                                          \
        if (k < NLAB && m < NLAB) e = __expf(trans[k * NLAB + m]);              \
        const unsigned short hb = f2bf(e);                                      \
        const float ef = __uint_as_float((unsigned)hb << 16);                   \
        const unsigned short lb = f2bf(e - ef);                                 \
        h[j] = (short)hb; l[j] = (short)lb;                                     \
    } DH = h; DL = l; }
    MKFRAG(ah00, al00, 0, 0) MKFRAG(ah01, al01, 0, 1)
    MKFRAG(ah02, al02, 0, 2) MKFRAG(ah03, al03, 0, 3)
    MKFRAG(ah10, al10, 1, 0) MKFRAG(ah11, al11, 1, 1)
    MKFRAG(ah12, al12, 1, 2) MKFRAG(ah13, al13, 1, 3)

    // ---- addresses / per-lane label maps ----
    const int rowbase = b16 * 128;
    const int swz = (b16 & 7) << 4;     // XOR-swizzle within batch row
    int wby[4][2];                      // write byte addr per (mt, pair)
    int emo[4][4];                      // clamped emission label offset
    bool vmask[4][4];                   // label valid (<50)
#pragma unroll
    for (int mt = 0; mt < 4; ++mt) {
        wby[mt][0] = rowbase + ((32 * mt + 8 * g)     ^ swz);
        wby[mt][1] = rowbase + ((32 * mt + 8 * g + 4) ^ swz);
#pragma unroll
        for (int r = 0; r < 4; ++r) {
            const int L = 16 * mt + 4 * g + r;
            emo[mt][r] = (L < NLAB) ? L : (NLAB - 1);
            vmask[mt][r] = (L < NLAB);
        }
    }
    const int rby0 = rowbase + ((16 * g)      ^ swz);   // B-frag kt=0
    const int rby1 = rowbase + ((64 + 16 * g) ^ swz);   // B-frag kt=1
    const int vby  = rowbase + swz;                     // label 0 scale value

    const float* emb = logits + (size_t)b * TLEN * NLAB;

    // ---- prologue: alpha0 = startT + em[0]; X0 = exp(a0 - a0[label0]) ----
    float a0[4][4];
#pragma unroll
    for (int mt = 0; mt < 4; ++mt)
#pragma unroll
        for (int r = 0; r < 4; ++r)
            a0[mt][r] = startT[emo[mt][r]] + emb[emo[mt][r]];
    const float a00 = __int_as_float(
        __builtin_amdgcn_ds_bpermute(b16 * 4, __float_as_int(a0[0][0])));
    float A = a00;

#pragma unroll
    for (int mt = 0; mt < 4; ++mt) {
        float w0 = vmask[mt][0] ? __expf(a0[mt][0] - a00) : 0.f;
        float w1 = vmask[mt][1] ? __expf(a0[mt][1] - a00) : 0.f;
        float w2 = vmask[mt][2] ? __expf(a0[mt][2] - a00) : 0.f;
        float w3 = vmask[mt][3] ? __expf(a0[mt][3] - a00) : 0.f;
        unsigned int u0, u1;
        asm("v_cvt_pk_bf16_f32 %0, %1, %2" : "=v"(u0) : "v"(w0), "v"(w1));
        asm("v_cvt_pk_bf16_f32 %0, %1, %2" : "=v"(u1) : "v"(w2), "v"(w3));
        *(unsigned int*)(xc + wby[mt][0]) = u0;
        *(unsigned int*)(xc + wby[mt][1]) = u1;
    }
    wave_lds_fence();
    short8 xb0 = *(const short8*)(xc + rby0);
    short8 xb1 = *(const short8*)(xc + rby1);

    // emission prefetch for t=1
    float pf[4][4];
    {
        const float* e1 = emb + NLAB;
#pragma unroll
        for (int mt = 0; mt < 4; ++mt)
#pragma unroll
            for (int r = 0; r < 4; ++r)
                pf[mt][r] = e1[emo[mt][r]];
    }

    for (int t = 1; t < lenmax; ++t) {
        const bool act = (t < len);
        // scale value: previous state's label-0 entry for this batch
        const unsigned short vus = *(const unsigned short*)(xc + vby);

        // prefetch next emission row
        const int tn = (t + 1 < lenmax) ? (t + 1) : (lenmax - 1);
        const float* en = emb + (size_t)tn * NLAB;
        float nf[4][4];
#pragma unroll
        for (int mt = 0; mt < 4; ++mt)
#pragma unroll
            for (int r = 0; r < 4; ++r)
                nf[mt][r] = en[emo[mt][r]];

        const float vf = __uint_as_float((unsigned)vus << 16);
        const float lg2v = __log2f(vf);
        A += act ? lg2v * LN2 : 0.f;

        // pe = exp(em) / v, fused in exp2 domain (off MFMA critical path)
        float pe[4][4];
#pragma unroll
        for (int mt = 0; mt < 4; ++mt)
#pragma unroll
            for (int r = 0; r < 4; ++r)
                pe[mt][r] = __builtin_amdgcn_exp2f(fmaf(pf[mt][r], LOG2E, -lg2v));

        // r = E^T X : 16 MFMAs, 4 chains of 4 (hi+lo per k-tile)
        f32x4 ac0 = {0.f,0.f,0.f,0.f}, ac1 = {0.f,0.f,0.f,0.f};
        f32x4 ac2 = {0.f,0.f,0.f,0.f}, ac3 = {0.f,0.f,0.f,0.f};
        ac0 = __builtin_amdgcn_mfma_f32_16x16x32_bf16(ah00, xb0, ac0, 0, 0, 0);
        ac0 = __builtin_amdgcn_mfma_f32_16x16x32_bf16(al00, xb0, ac0, 0, 0, 0);
        ac0 = __builtin_amdgcn_mfma_f32_16x16x32_bf16(ah10, xb1, ac0, 0, 0, 0);
        ac0 = __builtin_amdgcn_mfma_f32_16x16x32_bf16(al10, xb1, ac0, 0, 0, 0);
        ac1 = __builtin_amdgcn_mfma_f32_16x16x32_bf16(ah01, xb0, ac1, 0, 0, 0);
        ac1 = __builtin_amdgcn_mfma_f32_16x16x32_bf16(al01, xb0, ac1, 0, 0, 0);
        ac1 = __builtin_amdgcn_mfma_f32_16x16x32_bf16(ah11, xb1, ac1, 0, 0, 0);
        ac1 = __builtin_amdgcn_mfma_f32_16x16x32_bf16(al11, xb1, ac1, 0, 0, 0);
        ac2 = __builtin_amdgcn_mfma_f32_16x16x32_bf16(ah02, xb0, ac2, 0, 0, 0);
        ac2 = __builtin_amdgcn_mfma_f32_16x16x32_bf16(al02, xb0, ac2, 0, 0, 0);
        ac2 = __builtin_amdgcn_mfma_f32_16x16x32_bf16(ah12, xb1, ac2, 0, 0, 0);
        ac2 = __builtin_amdgcn_mfma_f32_16x16x32_bf16(al12, xb1, ac2, 0, 0, 0);
        ac3 = __builtin_amdgcn_mfma_f32_16x16x32_bf16(ah03, xb0, ac3, 0, 0, 0);
        ac3 = __builtin_amdgcn_mfma_f32_16x16x32_bf16(al03, xb0, ac3, 0, 0, 0);
        ac3 = __builtin_amdgcn_mfma_f32_16x16x32_bf16(ah13, xb1, ac3, 0, 0, 0);
        ac3 = __builtin_amdgcn_mfma_f32_16x16x32_bf16(al13, xb1, ac3, 0, 0, 0);

        // w = r * pe, pad labels -> 0, pack bf16 pairs
        unsigned int u00, u01, u10, u11, u20, u21, u30, u31;
#define WPACK(AC, MT, U0, U1) {                                                \
        float w0 = AC[0] * pe[MT][0];                                          \
        float w1 = AC[1] * pe[MT][1];                                          \
        float w2 = AC[2] * pe[MT][2];                                          \
        float w3 = AC[3] * pe[MT][3];                                          \
        if (!vmask[MT][0]) w0 = 0.f;                                           \
        if (!vmask[MT][1]) w1 = 0.f;                                           \
        if (!vmask[MT][2]) w2 = 0.f;                                           \
        if (!vmask[MT][3]) w3 = 0.f;                                           \
        asm("v_cvt_pk_bf16_f32 %0, %1, %2" : "=v"(U0) : "v"(w0), "v"(w1));     \
        asm("v_cvt_pk_bf16_f32 %0, %1, %2" : "=v"(U1) : "v"(w2), "v"(w3));     \
    }
        WPACK(ac0, 0, u00, u01)
        WPACK(ac1, 1, u10, u11)
        WPACK(ac2, 2, u20, u21)
        WPACK(ac3, 3, u30, u31)

        if (act) {   // frozen batches keep their previous X
            *(unsigned int*)(xc + wby[0][0]) = u00;
            *(unsigned int*)(xc + wby[0][1]) = u01;
            *(unsigned int*)(xc + wby[1][0]) = u10;
            *(unsigned int*)(xc + wby[1][1]) = u11;
            *(unsigned int*)(xc + wby[2][0]) = u20;
            *(unsigned int*)(xc + wby[2][1]) = u21;
            *(unsigned int*)(xc + wby[3][0]) = u30;
            *(unsigned int*)(xc + wby[3][1]) = u31;
        }
        wave_lds_fence();
        xb0 = *(const short8*)(xc + rby0);
        xb1 = *(const short8*)(xc + rby1);

#pragma unroll
        for (int mt = 0; mt < 4; ++mt)
#pragma unroll
            for (int r = 0; r < 4; ++r)
                pf[mt][r] = nf[mt][r];
    }

    // ---- den = A + log( sum_j X[j][b] * exp(endT[j]) ) ----
    float part = 0.f;
#pragma unroll
    for (int j = 0; j < 8; ++j) {
        const int k1 = 32 + 8 * g + j;                  // k0 = 8g+j is always <50
        const float x0 = __uint_as_float((unsigned)(unsigned short)xb0[j] << 16);
        const float x1 = __uint_as_float((unsigned)(unsigned short)xb1[j] << 16);
        const float e0 = __expf(endT[8 * g + j]);
        float e1 = 0.f;
        if (k1 < NLAB) e1 = __expf(endT[k1]);
        part = fmaf(x0, e0, part);
        part = fmaf(x1, e1, part);
    }
    part += __shfl_xor(part, 16, 64);
    part += __shfl_xor(part, 32, 64);
    const float den = A + __logf(part);

    // ---- numerator: gold path, chunked over g ----
    const int* tg = labels + (size_t)b * TLEN;
    float num = 0.f;
    {
        const int t0 = g * 128;
#pragma unroll 8
        for (int i = 0; i < 128; ++i) {
            const int t = t0 + i;
            if (t < len) {
                const int tag = tg[t];
                num += emb[(size_t)t * NLAB + tag];
                if (t >= 1) num += trans[tg[t - 1] * NLAB + tag];
            }
        }
    }
    num += __shfl_xor(num, 16, 64);
    num += __shfl_xor(num, 32, 64);
    if (g == 0) {
        num += startT[tg[0]] + endT[tg[len - 1]];
        atomicAdd(out0, (den - num) * (1.0f / BATCH));
    }
}

extern "C" void kernel_launch(void* const* d_in, const int* in_sizes, int n_in,
                              void* d_out, int out_size, void* d_ws, size_t ws_size,
                              hipStream_t stream) {
    (void)in_sizes; (void)n_in; (void)out_size; (void)ws_size;
    const float* emb    = (const float*)d_in[0];
    const int*   labels = (const int*)d_in[1];
    const void*  mask   = d_in[2];
    const float* W      = (const float*)d_in[3];
    const float* bias   = (const float*)d_in[4];
    const float* startT = (const float*)d_in[5];
    const float* endT   = (const float*)d_in[6];
    const float* trans  = (const float*)d_in[7];

    float* out    = (float*)d_out;
    float* logits = out + 1;
    unsigned short* Bt = (unsigned short*)((char*)d_ws + 512);  // 96 KiB bf16 W^T

    wprep_kernel<<<(64 * DIM + 255) / 256, 256, 0, stream>>>(W, Bt, out);
    gemm_kernel<<<(BATCH * TLEN) / 128, 512, 0, stream>>>(emb, Bt, bias, logits);
    crf_kernel<<<BATCH / 16, 64, 0, stream>>>(logits, labels, mask, startT, endT, trans, out);
}

// Round 6
// 453.708 us; speedup vs baseline: 1.3109x; 1.3109x over previous
//
#include <hip/hip_runtime.h>
#include <hip/hip_bf16.h>
#include <math.h>

#define BATCH 64
#define TLEN 512
#define DIM 768
#define NLAB 50

typedef __attribute__((ext_vector_type(8))) short short8;   // 8 bf16 (4 VGPRs)
typedef __attribute__((ext_vector_type(4))) float f32x4;    // MFMA acc

__device__ __forceinline__ unsigned short f2bf(float f) {
    unsigned int u = __float_as_uint(f);
    return (unsigned short)((u + 0x7FFFu + ((u >> 16) & 1u)) >> 16);
}

// single-wave LDS fence: legal ONLY for 64-thread (one-wave) blocks.
__device__ __forceinline__ void wave_lds_fence() {
    __asm__ __volatile__("s_waitcnt lgkmcnt(0)" ::: "memory");
    __builtin_amdgcn_wave_barrier();
}

// ---------------------------------------------------------------------------
// prep: W fp32 [768 x 50] -> Bt bf16 [64 cols][768 k]; zero out[0] for atomics
// ---------------------------------------------------------------------------
__global__ __launch_bounds__(256) void wprep_kernel(const float* __restrict__ W,
                                                    unsigned short* __restrict__ Bt,
                                                    float* __restrict__ out0) {
    int idx = blockIdx.x * 256 + threadIdx.x;
    if (idx == 0) out0[0] = 0.f;
    if (idx < 64 * DIM) {
        int c = idx / DIM;
        int k = idx - c * DIM;
        float v = (c < NLAB) ? W[k * NLAB + c] : 0.f;
        Bt[idx] = f2bf(v);
    }
}

// ---------------------------------------------------------------------------
// GEMM: 512 thr / 8 waves, tile 128x64, dbuf LDS. Epilogue optionally also
// writes exp(logits) to an ALIGNED workspace buffer (eexp) so the CRF scan
// needs no per-step transcendentals and can use float2 loads.
// ---------------------------------------------------------------------------
#define AST 36
#define BSTC 40

__global__ __launch_bounds__(512)
void gemm_kernel(
    const float* __restrict__ A,
    const unsigned short* __restrict__ Bt,
    const float* __restrict__ bias,
    float* __restrict__ out,
    float* __restrict__ eexp)                 // may be null
{
    __shared__ float As[2][128 * AST];
    __shared__ short Bs[2][64 * BSTC];

    const int tid = threadIdx.x;
    const int wave = tid >> 6;
    const int lane = tid & 63;
    const int m = lane & 15;
    const int q = lane >> 4;
    const int row0 = blockIdx.x * 128;

    const int r0s = tid >> 2;
    const int c0s = (tid & 3) * 8;
    const int bcol = tid >> 3;
    const int bkk = (tid & 7) * 4;

    f32x4 acc0 = {0.f,0.f,0.f,0.f}, acc1 = {0.f,0.f,0.f,0.f};
    f32x4 acc2 = {0.f,0.f,0.f,0.f}, acc3 = {0.f,0.f,0.f,0.f};

    {
        *(float4*)&As[0][r0s * AST + c0s]     = *(const float4*)(A + (size_t)(row0 + r0s) * DIM + c0s);
        *(float4*)&As[0][r0s * AST + c0s + 4] = *(const float4*)(A + (size_t)(row0 + r0s) * DIM + c0s + 4);
        *(short4*)&Bs[0][bcol * BSTC + bkk]   = *(const short4*)(Bt + (size_t)bcol * DIM + bkk);
    }
    __syncthreads();

    int buf = 0;
    for (int ch = 0; ch < DIM / 32; ++ch) {
        const int k0n = (ch + 1) * 32;
        const bool havenext = (ch < DIM / 32 - 1);
        float4 pa0, pa1;
        short4 pb;
        if (havenext) {
            pa0 = *(const float4*)(A + (size_t)(row0 + r0s) * DIM + k0n + c0s);
            pa1 = *(const float4*)(A + (size_t)(row0 + r0s) * DIM + k0n + c0s + 4);
            pb  = *(const short4*)(Bt + (size_t)bcol * DIM + k0n + bkk);
        }

        const short8 bq0 = *(const short8*)&Bs[buf][( 0 + m) * BSTC + q * 8];
        const short8 bq1 = *(const short8*)&Bs[buf][(16 + m) * BSTC + q * 8];
        const short8 bq2 = *(const short8*)&Bs[buf][(32 + m) * BSTC + q * 8];
        const short8 bq3 = *(const short8*)&Bs[buf][(48 + m) * BSTC + q * 8];

        {
            const int rr = wave * 16 + m;
            const float4 xa = *(const float4*)&As[buf][rr * AST + q * 8];
            const float4 xb = *(const float4*)&As[buf][rr * AST + q * 8 + 4];
            short8 af;
            af[0] = (short)f2bf(xa.x); af[1] = (short)f2bf(xa.y);
            af[2] = (short)f2bf(xa.z); af[3] = (short)f2bf(xa.w);
            af[4] = (short)f2bf(xb.x); af[5] = (short)f2bf(xb.y);
            af[6] = (short)f2bf(xb.z); af[7] = (short)f2bf(xb.w);
            acc0 = __builtin_amdgcn_mfma_f32_16x16x32_bf16(af, bq0, acc0, 0, 0, 0);
            acc1 = __builtin_amdgcn_mfma_f32_16x16x32_bf16(af, bq1, acc1, 0, 0, 0);
            acc2 = __builtin_amdgcn_mfma_f32_16x16x32_bf16(af, bq2, acc2, 0, 0, 0);
            acc3 = __builtin_amdgcn_mfma_f32_16x16x32_bf16(af, bq3, acc3, 0, 0, 0);
        }

        if (havenext) {
            const int nb = buf ^ 1;
            *(float4*)&As[nb][r0s * AST + c0s]     = pa0;
            *(float4*)&As[nb][r0s * AST + c0s + 4] = pa1;
            *(short4*)&Bs[nb][bcol * BSTC + bkk]   = pb;
        }
        __syncthreads();
        buf ^= 1;
    }

    const int rb = row0 + wave * 16 + q * 4;
#pragma unroll
    for (int nt = 0; nt < 4; ++nt) {
        const f32x4 av = (nt == 0) ? acc0 : (nt == 1) ? acc1 : (nt == 2) ? acc2 : acc3;
        const int col = nt * 16 + m;
        if (col < NLAB) {
            const float bv = bias[col];
#pragma unroll
            for (int r = 0; r < 4; ++r) {
                const float v = av[r] + bv;
                out[(size_t)(rb + r) * NLAB + col] = v;
                if (eexp) eexp[(size_t)(rb + r) * NLAB + col] = __expf(v);
            }
        }
    }
}

// ---------------------------------------------------------------------------
// CRF v12: MFMA scan, de-stalled.
// vs v11b (449us, 2110 cyc/step): (1) emission prefetch depth 2 (+unroll 2
// renaming) so L3/HBM latency (~600-900cy) is covered; (2) EEX path: gemm
// pre-computes exp(logits) into aligned ws -> pe = eex*rcp(v), zero per-step
// transcendentals except one log2, float2 loads (8 vs 16); (3) scale v taken
// from raw fp32 w0 via ds_bpermute at step end (drops the post-fence
// ds_read_u16 + log2 off the critical path; any consistent v preserves the
// invariant, frozen batches never consume a stale v since mask is a prefix);
// (4) hi/lo MFMA chains split (depth 4 -> 2) + vector add (D!=C is legal,
// zero C-init is a loop-invariant constant).
// ---------------------------------------------------------------------------
#define LOG2E 1.44269504088896340736f
#define LN2   0.69314718055994530942f

template<bool EEX>
__global__ __launch_bounds__(64) __attribute__((amdgpu_waves_per_eu(1, 1)))
void crf_kernel(
    const float* __restrict__ logits,
    const float* __restrict__ eex,
    const int* __restrict__ labels,
    const void* __restrict__ maskp,
    const float* __restrict__ startT,
    const float* __restrict__ endT,
    const float* __restrict__ trans,
    float* __restrict__ out0) {
    const int lane = threadIdx.x;
    const int b16 = lane & 15;           // batch within block
    const int g = lane >> 4;             // quad group
    const int b = blockIdx.x * 16 + b16; // global batch

    __shared__ __align__(16) unsigned short X[16 * 64]; // [batch][label] bf16
    char* xc = (char*)X;

    // ---- len_b: chunked mask scan (chunk c = g covers 128 t's) ----
    const int probe = ((const int*)maskp)[0];
    int len = 0;
    {
        const int t0 = g * 128;
        if (probe == 1) {
            const int* mk = (const int*)maskp + (size_t)b * TLEN + t0;
#pragma unroll 8
            for (int i = 0; i < 128; ++i) len += (mk[i] != 0);
        } else if (probe == 0x01010101) {
            const unsigned char* mk = (const unsigned char*)maskp + (size_t)b * TLEN + t0;
#pragma unroll 8
            for (int i = 0; i < 128; ++i) len += (mk[i] != 0);
        } else if (probe == 0x3F803F80) {
            const unsigned short* mk = (const unsigned short*)maskp + (size_t)b * TLEN + t0;
#pragma unroll 8
            for (int i = 0; i < 128; ++i) len += (mk[i] != 0);
        } else {
            const float* mk = (const float*)maskp + (size_t)b * TLEN + t0;
#pragma unroll 8
            for (int i = 0; i < 128; ++i) len += (mk[i] != 0.f);
        }
    }
    len += __shfl_xor(len, 16, 64);
    len += __shfl_xor(len, 32, 64);
    int lenmax = len;
    { int o = __shfl_xor(lenmax, 1, 64); lenmax = lenmax > o ? lenmax : o; }
    { int o = __shfl_xor(lenmax, 2, 64); lenmax = lenmax > o ? lenmax : o; }
    { int o = __shfl_xor(lenmax, 4, 64); lenmax = lenmax > o ? lenmax : o; }
    { int o = __shfl_xor(lenmax, 8, 64); lenmax = lenmax > o ? lenmax : o; }

    // ---- E^T fragments: A[m][k] = exp(trans[k][m]), hi/lo bf16, zero-pad ----
    short8 ah00, ah01, ah02, ah03, ah10, ah11, ah12, ah13;
    short8 al00, al01, al02, al03, al10, al11, al12, al13;
#define MKFRAG(DH, DL, KT, MT) { short8 h, l;                                   \
    _Pragma("unroll")                                                           \
    for (int j = 0; j < 8; ++j) {                                               \
        const int k = 32 * KT + 8 * g + j; const int m = 16 * MT + b16;         \
        float e = 0.f;                                                          \
        if (k < NLAB && m < NLAB) e = __expf(trans[k * NLAB + m]);              \
        const unsigned short hb = f2bf(e);                                      \
        const float ef = __uint_as_float((unsigned)hb << 16);                   \
        const unsigned short lb = f2bf(e - ef);                                 \
        h[j] = (short)hb; l[j] = (short)lb;                                     \
    } DH = h; DL = l; }
    MKFRAG(ah00, al00, 0, 0) MKFRAG(ah01, al01, 0, 1)
    MKFRAG(ah02, al02, 0, 2) MKFRAG(ah03, al03, 0, 3)
    MKFRAG(ah10, al10, 1, 0) MKFRAG(ah11, al11, 1, 1)
    MKFRAG(ah12, al12, 1, 2) MKFRAG(ah13, al13, 1, 3)

    // ---- addresses / per-lane label maps ----
    const int rowbase = b16 * 128;
    const int swz = (b16 & 7) << 4;
    int wby[4];                          // 8B write addr per mt (labels 16mt+4g..+3)
    int emo[4][4];
    bool vmask[4][4];
#pragma unroll
    for (int mt = 0; mt < 4; ++mt) {
        wby[mt] = rowbase + ((32 * mt + 8 * g) ^ swz);
#pragma unroll
        for (int r = 0; r < 4; ++r) {
            const int L = 16 * mt + 4 * g + r;
            emo[mt][r] = (L < NLAB) ? L : (NLAB - 1);
            vmask[mt][r] = (L < NLAB);
        }
    }
    const int rby0 = rowbase + ((16 * g)      ^ swz);
    const int rby1 = rowbase + ((64 + 16 * g) ^ swz);

    const float* emb = logits + (size_t)b * TLEN * NLAB;
    const float* emsrc = EEX ? (eex + (size_t)b * TLEN * NLAB) : emb;

    // ---- prologue: alpha0 = startT + em[0]; X0 = exp(a0 - a0[label0]) ----
    float a0[4][4];
#pragma unroll
    for (int mt = 0; mt < 4; ++mt)
#pragma unroll
        for (int r = 0; r < 4; ++r)
            a0[mt][r] = startT[emo[mt][r]] + emb[emo[mt][r]];
    const float a00 = __int_as_float(
        __builtin_amdgcn_ds_bpermute(b16 * 4, __float_as_int(a0[0][0])));
    float A = a00;

#pragma unroll
    for (int mt = 0; mt < 4; ++mt) {
        float w0 = vmask[mt][0] ? __expf(a0[mt][0] - a00) : 0.f;
        float w1 = vmask[mt][1] ? __expf(a0[mt][1] - a00) : 0.f;
        float w2 = vmask[mt][2] ? __expf(a0[mt][2] - a00) : 0.f;
        float w3 = vmask[mt][3] ? __expf(a0[mt][3] - a00) : 0.f;
        unsigned int u0, u1;
        asm("v_cvt_pk_bf16_f32 %0, %1, %2" : "=v"(u0) : "v"(w0), "v"(w1));
        asm("v_cvt_pk_bf16_f32 %0, %1, %2" : "=v"(u1) : "v"(w2), "v"(w3));
        uint2 p; p.x = u0; p.y = u1;
        *(uint2*)(xc + wby[mt]) = p;
    }
    wave_lds_fence();
    short8 xb0 = *(const short8*)(xc + rby0);
    short8 xb1 = *(const short8*)(xc + rby1);

    // emission stage loads: EEX -> float2 pairs (aligned ws), else scalars
#define LOADSTAGE(dst, row) {                                                   \
        const float* ep = emsrc + (size_t)(row) * NLAB;                         \
        _Pragma("unroll")                                                       \
        for (int mt_ = 0; mt_ < 4; ++mt_) {                                     \
            if constexpr (EEX) {                                                \
                const float2 p0_ = *(const float2*)(ep + 16 * mt_ + 4 * g);     \
                const float2 p1_ = *(const float2*)(ep + 16 * mt_ + 4 * g + 2); \
                dst[mt_][0] = p0_.x; dst[mt_][1] = p0_.y;                       \
                dst[mt_][2] = p1_.x; dst[mt_][3] = p1_.y;                       \
            } else {                                                            \
                _Pragma("unroll")                                               \
                for (int r_ = 0; r_ < 4; ++r_)                                  \
                    dst[mt_][r_] = ep[emo[mt_][r_]];                            \
            }                                                                   \
        } }

    float s0[4][4], s1[4][4];
    LOADSTAGE(s0, 1)
    LOADSTAGE(s1, (2 < lenmax) ? 2 : (lenmax - 1))
    float vwf = 1.0f;   // raw scale X(t-1)[label0]; exp(a00-a00)=1 at t=1

    const f32x4 z4 = {0.f, 0.f, 0.f, 0.f};

#pragma unroll 2
    for (int t = 1; t < lenmax; ++t) {
        const bool act = (t < len);
        const float lg2v = __log2f(vwf);
        const float rv = __builtin_amdgcn_rcpf(vwf);
        A += act ? lg2v * LN2 : 0.f;

        // prefetch emissions for t+2 (consumed 2 iterations from now)
        float s2[4][4];
        { int tn = t + 2; tn = (tn < lenmax) ? tn : (lenmax - 1); LOADSTAGE(s2, tn) }

        // pe = exp(em)/v, masked (also kills NaN/garbage from padded labels)
        float pe[4][4];
#pragma unroll
        for (int mt = 0; mt < 4; ++mt)
#pragma unroll
            for (int r = 0; r < 4; ++r) {
                float p;
                if constexpr (EEX) p = s0[mt][r] * rv;
                else p = __builtin_amdgcn_exp2f(fmaf(s0[mt][r], LOG2E, -lg2v));
                pe[mt][r] = vmask[mt][r] ? p : 0.f;
            }

        // r = E^T X : hi/lo split accumulators, chains of depth 2
        f32x4 h0 = __builtin_amdgcn_mfma_f32_16x16x32_bf16(ah00, xb0, z4, 0, 0, 0);
        h0 = __builtin_amdgcn_mfma_f32_16x16x32_bf16(ah10, xb1, h0, 0, 0, 0);
        f32x4 l0 = __builtin_amdgcn_mfma_f32_16x16x32_bf16(al00, xb0, z4, 0, 0, 0);
        l0 = __builtin_amdgcn_mfma_f32_16x16x32_bf16(al10, xb1, l0, 0, 0, 0);
        f32x4 h1 = __builtin_amdgcn_mfma_f32_16x16x32_bf16(ah01, xb0, z4, 0, 0, 0);
        h1 = __builtin_amdgcn_mfma_f32_16x16x32_bf16(ah11, xb1, h1, 0, 0, 0);
        f32x4 l1 = __builtin_amdgcn_mfma_f32_16x16x32_bf16(al01, xb0, z4, 0, 0, 0);
        l1 = __builtin_amdgcn_mfma_f32_16x16x32_bf16(al11, xb1, l1, 0, 0, 0);
        f32x4 h2 = __builtin_amdgcn_mfma_f32_16x16x32_bf16(ah02, xb0, z4, 0, 0, 0);
        h2 = __builtin_amdgcn_mfma_f32_16x16x32_bf16(ah12, xb1, h2, 0, 0, 0);
        f32x4 l2 = __builtin_amdgcn_mfma_f32_16x16x32_bf16(al02, xb0, z4, 0, 0, 0);
        l2 = __builtin_amdgcn_mfma_f32_16x16x32_bf16(al12, xb1, l2, 0, 0, 0);
        f32x4 h3 = __builtin_amdgcn_mfma_f32_16x16x32_bf16(ah03, xb0, z4, 0, 0, 0);
        h3 = __builtin_amdgcn_mfma_f32_16x16x32_bf16(ah13, xb1, h3, 0, 0, 0);
        f32x4 l3 = __builtin_amdgcn_mfma_f32_16x16x32_bf16(al03, xb0, z4, 0, 0, 0);
        l3 = __builtin_amdgcn_mfma_f32_16x16x32_bf16(al13, xb1, l3, 0, 0, 0);

        const float w00 = (h0[0] + l0[0]) * pe[0][0];
        const float w01 = (h0[1] + l0[1]) * pe[0][1];
        const float w02 = (h0[2] + l0[2]) * pe[0][2];
        const float w03 = (h0[3] + l0[3]) * pe[0][3];
        const float w10 = (h1[0] + l1[0]) * pe[1][0];
        const float w11 = (h1[1] + l1[1]) * pe[1][1];
        const float w12 = (h1[2] + l1[2]) * pe[1][2];
        const float w13 = (h1[3] + l1[3]) * pe[1][3];
        const float w20 = (h2[0] + l2[0]) * pe[2][0];
        const float w21 = (h2[1] + l2[1]) * pe[2][1];
        const float w22 = (h2[2] + l2[2]) * pe[2][2];
        const float w23 = (h2[3] + l2[3]) * pe[2][3];
        const float w30 = (h3[0] + l3[0]) * pe[3][0];
        const float w31 = (h3[1] + l3[1]) * pe[3][1];
        const float w32 = (h3[2] + l3[2]) * pe[3][2];
        const float w33 = (h3[3] + l3[3]) * pe[3][3];

        // next-step scale: raw fp32 label0 value, broadcast down the column
        // (issued before the divergent write block; fence below drains it)
        const float vwn = __int_as_float(
            __builtin_amdgcn_ds_bpermute(b16 * 4, __float_as_int(w00)));

        uint2 p0, p1, p2, p3;
        asm("v_cvt_pk_bf16_f32 %0, %1, %2" : "=v"(p0.x) : "v"(w00), "v"(w01));
        asm("v_cvt_pk_bf16_f32 %0, %1, %2" : "=v"(p0.y) : "v"(w02), "v"(w03));
        asm("v_cvt_pk_bf16_f32 %0, %1, %2" : "=v"(p1.x) : "v"(w10), "v"(w11));
        asm("v_cvt_pk_bf16_f32 %0, %1, %2" : "=v"(p1.y) : "v"(w12), "v"(w13));
        asm("v_cvt_pk_bf16_f32 %0, %1, %2" : "=v"(p2.x) : "v"(w20), "v"(w21));
        asm("v_cvt_pk_bf16_f32 %0, %1, %2" : "=v"(p2.y) : "v"(w22), "v"(w23));
        asm("v_cvt_pk_bf16_f32 %0, %1, %2" : "=v"(p3.x) : "v"(w30), "v"(w31));
        asm("v_cvt_pk_bf16_f32 %0, %1, %2" : "=v"(p3.y) : "v"(w32), "v"(w33));

        if (act) {   // frozen batches keep their previous X
            *(uint2*)(xc + wby[0]) = p0;
            *(uint2*)(xc + wby[1]) = p1;
            *(uint2*)(xc + wby[2]) = p2;
            *(uint2*)(xc + wby[3]) = p3;
        }
        wave_lds_fence();
        xb0 = *(const short8*)(xc + rby0);
        xb1 = *(const short8*)(xc + rby1);

        // rotate emission stages (renamed away by unroll 2)
#pragma unroll
        for (int mt = 0; mt < 4; ++mt)
#pragma unroll
            for (int r = 0; r < 4; ++r) { s0[mt][r] = s1[mt][r]; s1[mt][r] = s2[mt][r]; }
        vwf = vwn;
    }

    // ---- den = A + log( sum_j X[j][b] * exp(endT[j]) ) ----
    float part = 0.f;
#pragma unroll
    for (int j = 0; j < 8; ++j) {
        const int k1 = 32 + 8 * g + j;
        const float x0 = __uint_as_float((unsigned)(unsigned short)xb0[j] << 16);
        const float x1 = __uint_as_float((unsigned)(unsigned short)xb1[j] << 16);
        const float e0 = __expf(endT[8 * g + j]);
        float e1 = 0.f;
        if (k1 < NLAB) e1 = __expf(endT[k1]);
        part = fmaf(x0, e0, part);
        part = fmaf(x1, e1, part);
    }
    part += __shfl_xor(part, 16, 64);
    part += __shfl_xor(part, 32, 64);
    const float den = A + __logf(part);

    // ---- numerator: gold path, chunked over g ----
    const int* tg = labels + (size_t)b * TLEN;
    float num = 0.f;
    {
        const int t0 = g * 128;
#pragma unroll 8
        for (int i = 0; i < 128; ++i) {
            const int t = t0 + i;
            if (t < len) {
                const int tag = tg[t];
                num += emb[(size_t)t * NLAB + tag];
                if (t >= 1) num += trans[tg[t - 1] * NLAB + tag];
            }
        }
    }
    num += __shfl_xor(num, 16, 64);
    num += __shfl_xor(num, 32, 64);
    if (g == 0) {
        num += startT[tg[0]] + endT[tg[len - 1]];
        atomicAdd(out0, (den - num) * (1.0f / BATCH));
    }
}

extern "C" void kernel_launch(void* const* d_in, const int* in_sizes, int n_in,
                              void* d_out, int out_size, void* d_ws, size_t ws_size,
                              hipStream_t stream) {
    (void)in_sizes; (void)n_in; (void)out_size;
    const float* emb    = (const float*)d_in[0];
    const int*   labels = (const int*)d_in[1];
    const void*  mask   = d_in[2];
    const float* W      = (const float*)d_in[3];
    const float* bias   = (const float*)d_in[4];
    const float* startT = (const float*)d_in[5];
    const float* endT   = (const float*)d_in[6];
    const float* trans  = (const float*)d_in[7];

    float* out    = (float*)d_out;
    float* logits = out + 1;
    unsigned short* Bt = (unsigned short*)((char*)d_ws + 512);   // 96 KiB bf16 W^T
    float* eex = (float*)((char*)d_ws + (128 << 10));            // aligned exp(logits)

    const size_t need = (size_t)(128 << 10)
                      + sizeof(float) * ((size_t)BATCH * TLEN * NLAB + 256);
    const bool use_eex = (ws_size >= need);

    wprep_kernel<<<(64 * DIM + 255) / 256, 256, 0, stream>>>(W, Bt, out);
    gemm_kernel<<<(BATCH * TLEN) / 128, 512, 0, stream>>>(emb, Bt, bias, logits,
                                                          use_eex ? eex : nullptr);
    if (use_eex)
        crf_kernel<true><<<BATCH / 16, 64, 0, stream>>>(logits, eex, labels, mask,
                                                        startT, endT, trans, out);
    else
        crf_kernel<false><<<BATCH / 16, 64, 0, stream>>>(logits, nullptr, labels, mask,
                                                         startT, endT, trans, out);
}